// Round 4
// baseline (426.005 us; speedup 1.0000x reference)
//
#include <hip/hip_runtime.h>

// SimpleRNN: T=64, B=8, H=512, I=256, O=8, G=4, GS=64
// sign: +1 for j<=408, -1 for j>=409; exist: j<410
// chunk c: j = lane + 64c. c<6 -> sign +1; c==7 -> sign -1 (and exist=0);
// c==6 -> lane<=24: +1, lane==25: -1(exists), lane>=26: j>=410 (no exist).
#define T_N 64
#define B_N 8
#define H_N 512
#define I_N 256
#define O_N 8
#define G_N 4

constexpr float DT_  = 0.02f;
constexpr float AX_  = 0.2f;    // DT/0.1
constexpr float AW_  = 0.02f;   // DT/1.0
constexpr float OMAW = 1.0f - AW_;

using u64 = unsigned long long;

// Agent-scope coherent ops (sc0/sc1: bypass non-coherent L1/L2, hit LLC).
__device__ __forceinline__ float ldf_agent(const float* p) {
    return __hip_atomic_load(p, __ATOMIC_RELAXED, __HIP_MEMORY_SCOPE_AGENT);
}
__device__ __forceinline__ void stf_agent(float* p, float v) {
    __hip_atomic_store(p, v, __ATOMIC_RELAXED, __HIP_MEMORY_SCOPE_AGENT);
}
__device__ __forceinline__ u64 ld64_agent(const u64* p) {
    return __hip_atomic_load(p, __ATOMIC_RELAXED, __HIP_MEMORY_SCOPE_AGENT);
}
__device__ __forceinline__ void st64_agent(u64* p, u64 v) {
    __hip_atomic_store(p, v, __ATOMIC_RELAXED, __HIP_MEMORY_SCOPE_AGENT);
}
__device__ __forceinline__ unsigned ldu_agent(const unsigned* p) {
    return __hip_atomic_load(p, __ATOMIC_RELAXED, __HIP_MEMORY_SCOPE_AGENT);
}

__device__ __forceinline__ float fast_tanh_pos(float x) {
    // x >= 0; exact at 0 and +inf. tanh(x) = 1 - 2/(e^{2x}+1)
    float ex = __expf(2.0f * x);
    return 1.0f - 2.0f / (ex + 1.0f);
}

// 256 blocks x 512 threads = 2048 waves; wave owns h0=hg*16+wid*2 and h0+1.
// b = bk & 7 ; hg = bk >> 3 (0..31). NO barriers in the main loop: each wave
// publishes tagged outputs and each lane polls only its own 8 comm words.
__global__ __launch_bounds__(512, 2) void rnn_scan(
    const float* __restrict__ x, const float* __restrict__ Rs,
    const float* __restrict__ W_x2h, const float* __restrict__ W_h2h,
    const float* __restrict__ b_h2h, const float* __restrict__ W_h2o,
    const float* __restrict__ W_attn, const float* __restrict__ b_attn,
    const float* __restrict__ kappa, float* __restrict__ d_out,
    u64* __restrict__ comm, unsigned* __restrict__ barrier_cnt)
{
    float* os = d_out;                      // [T][B][O]
    float* hs = d_out + T_N * B_N * O_N;    // [T][B][H]

    const int tid  = threadIdx.x;
    const int wid  = tid >> 6;              // 0..7
    const int lane = tid & 63;
    const int bk   = blockIdx.x;            // 0..255
    const int b    = bk & 7;
    const int hg   = bk >> 3;               // 0..31
    const int h0   = (hg << 4) | (wid << 1);
    const int h1   = h0 + 1;
    const int c_d  = hg >> 2;               // chunk containing this block's diagonal
    const int dl0  = h0 & 63, dl1 = h1 & 63;

    // ---- loop-invariant constants (registers only) ----
    // attn: eff_attn[g][j] = relu(W_attn)*sign*exist  (c==7 is all-zero)
    float ea[G_N][7];
#pragma unroll
    for (int g = 0; g < G_N; ++g)
#pragma unroll
        for (int c = 0; c < 7; ++c) {
            int j = lane + 64 * c;
            float w = fmaxf(W_attn[g * H_N + j], 0.0f);
            float m = (j <= 408) ? 1.0f : ((j == 409) ? -1.0f : 0.0f);
            ea[g][c] = w * m;
        }

    // x-side effective weights: ex = Wxp + wx (>=0), init ex = Wxp; bwx = AW*Wxp
    float ex0[4], ex1[4], bwx0[4], bwx1[4];
#pragma unroll
    for (int c = 0; c < 4; ++c) {
        ex0[c]  = fmaxf(W_x2h[h0 * I_N + lane + 64 * c], 0.0f);
        bwx0[c] = AW_ * ex0[c];
        ex1[c]  = fmaxf(W_x2h[h1 * I_N + lane + 64 * c], 0.0f);
        bwx1[c] = AW_ * ex1[c];
    }
    // h2h signed effective weights: se = sign*(Whp+wh), init sign*Whp (0 at diag)
    float se0[8], se1[8], bwh0[8], bwh1[8];
#pragma unroll
    for (int c = 0; c < 8; ++c) {
        int j = lane + 64 * c;
        float s  = (j <= 408) ? 1.0f : -1.0f;
        float w0 = fmaxf(W_h2h[h0 * H_N + j], 0.0f);
        float w1 = fmaxf(W_h2h[h1 * H_N + j], 0.0f);
        se0[c]  = (j == h0) ? 0.0f : s * w0;
        se1[c]  = (j == h1) ? 0.0f : s * w1;
        bwh0[c] = AW_ * w0;
        bwh1[c] = AW_ * w1;
    }
    const float bh0 = b_h2h[h0], bh1 = b_h2h[h1];
    const float k0 = kappa[0], k1 = kappa[1], k2 = kappa[2];
    const float k3 = kappa[3], k4 = kappa[4], k5 = kappa[5];
    const float ba0 = b_attn[0], ba1 = b_attn[1], ba2 = b_attn[2], ba3 = b_attn[3];

    float st0 = 0.0f, st1 = 0.0f;

    float xv[4];
#pragma unroll
    for (int c = 0; c < 4; ++c) xv[c] = fmaxf(x[(size_t)b * I_N + lane + 64 * c], 0.0f);
    float Rcur = Rs[b];

    float outp[8];
#pragma unroll
    for (int c = 0; c < 8; ++c) outp[c] = 0.0f;   // t=0 inputs are zeros

    for (int t = 0; t < T_N; ++t) {
        // ---- 14 fused wave reductions ----
        float red[14];
#pragma unroll
        for (int g = 0; g < G_N; ++g) {
            float l = 0.0f;
#pragma unroll
            for (int c = 0; c < 7; ++c) l = fmaf(outp[c], ea[g][c], l);
            red[g] = l;
        }
#pragma unroll
        for (int c = 0; c < 4; ++c) { red[4 + c] = ex0[c] * xv[c]; red[9 + c] = ex1[c] * xv[c]; }
        {
            float a0 = 0.0f, a1 = 0.0f;
#pragma unroll
            for (int c = 0; c < 8; ++c) { a0 = fmaf(se0[c], outp[c], a0); a1 = fmaf(se1[c], outp[c], a1); }
            red[8] = a0; red[13] = a1;
        }
#pragma unroll
        for (int off = 32; off >= 1; off >>= 1) {
#pragma unroll
            for (int k = 0; k < 14; ++k) red[k] += __shfl_xor(red[k], off, 64);
        }

        // ---- softmax over 4 logits; |logit| <~ 26 so no max-shift needed ----
        float e0 = __expf(red[0] + ba0), e1 = __expf(red[1] + ba1);
        float e2 = __expf(red[2] + ba2), e3 = __expf(red[3] + ba3);
        float inv = 4.0f / (e0 + e1 + e2 + e3);     // fold *G
        float aw0 = e0 * inv, aw1 = e1 * inv, aw2 = e2 * inv, aw3 = e3 * inv;

        float tot0 = red[4] * aw0 + red[5] * aw1 + red[6] * aw2 + red[7] * aw3 + red[8]  + bh0;
        float tot1 = red[9] * aw0 + red[10] * aw1 + red[11] * aw2 + red[12] * aw3 + red[13] + bh1;

        st0 = st0 * (1.0f - AX_) + tot0 * AX_;
        st1 = st1 * (1.0f - AX_) + tot1 * AX_;
        float no0 = fast_tanh_pos(fmaxf(st0, 0.0f));
        float no1 = fast_tanh_pos(fmaxf(st1, 0.0f));

        // ---- publish immediately (tagged comm + hs), fire-and-forget ----
        u64* crow = comm + ((size_t)(t & 1) * B_N + b) * H_N;
        if (lane == 0) {
            union { float f; unsigned u; } c0, c1; c0.f = no0; c1.f = no1;
            u64 hi = (u64)(unsigned)(t + 1) << 32;
            st64_agent(crow + h0, hi | (u64)c0.u);
            st64_agent(crow + h1, hi | (u64)c1.u);
            float* hrow = hs + ((size_t)t * B_N + b) * H_N;
            stf_agent(hrow + h0, no0);
            stf_agent(hrow + h1, no1);
        }

        // ---- next-step input prefetch (in flight during plasticity+poll) ----
        float xvn[4] = {0.f, 0.f, 0.f, 0.f};
        float Rn = 0.0f;
        if (t + 1 < T_N) {
            const float* xr = x + ((size_t)(t + 1) * B_N + b) * I_N;
#pragma unroll
            for (int c = 0; c < 4; ++c) xvn[c] = xr[lane + 64 * c];
            Rn = Rs[(t + 1) * B_N + b];
        }

        // ---- plasticity update (off the critical path) ----
        float xin[4] = { xv[0] * aw0, xv[1] * aw1, xv[2] * aw2, xv[3] * aw3 };
        float dr = DT_ * Rcur;
        float k1n0 = k1 * no0, k2n0 = k2 * no0, k4n0 = k4 * no0, k5n0 = k5 * no0;
        float k1n1 = k1 * no1, k2n1 = k2 * no1, k4n1 = k4 * no1, k5n1 = k5 * no1;
#pragma unroll
        for (int c = 0; c < 4; ++c) {
            float hx0 = fmaf(k2n0, xin[c], fmaf(k0, xin[c], k1n0));
            float hx1 = fmaf(k2n1, xin[c], fmaf(k0, xin[c], k1n1));
            ex0[c] = fmaxf(fmaf(ex0[c], OMAW, fmaf(dr, hx0, bwx0[c])), 0.0f);
            ex1[c] = fmaxf(fmaf(ex1[c], OMAW, fmaf(dr, hx1, bwx1[c])), 0.0f);
        }
#pragma unroll
        for (int c = 0; c < 8; ++c) {
            float hh0 = fmaf(k5n0, outp[c], fmaf(k3, outp[c], k4n0));
            float hh1 = fmaf(k5n1, outp[c], fmaf(k3, outp[c], k4n1));
            float a0 = se0[c] * OMAW, p0 = fmaf(dr, hh0, bwh0[c]);
            float a1 = se1[c] * OMAW, p1 = fmaf(dr, hh1, bwh1[c]);
            float r0, r1;
            if (c <= 5)      { r0 = fmaxf(a0 + p0, 0.0f); r1 = fmaxf(a1 + p1, 0.0f); }
            else if (c == 7) { r0 = fminf(a0 - p0, 0.0f); r1 = fminf(a1 - p1, 0.0f); }
            else {
                bool pos = (lane <= 24);
                r0 = pos ? fmaxf(a0 + p0, 0.0f) : fminf(a0 - p0, 0.0f);
                r1 = pos ? fmaxf(a1 + p1, 0.0f) : fminf(a1 - p1, 0.0f);
            }
            if (c == c_d) {                    // block-uniform: keep diagonal at 0
                if (lane == dl0) r0 = 0.0f;
                if (lane == dl1) r1 = 0.0f;
            }
            se0[c] = r0; se1[c] = r1;
        }

        // ---- per-lane poll of own 8 tagged words (no barriers, no counters) ----
        if (t + 1 < T_N) {
            const unsigned want = (unsigned)(t + 1);
            unsigned done = 0;
            float outn[8];
#pragma unroll
            for (int c = 0; c < 8; ++c) outn[c] = 0.0f;
            while (true) {
#pragma unroll
                for (int c = 0; c < 8; ++c) {
                    if (!(done & (1u << c))) {
                        u64 pk = ld64_agent(crow + lane + 64 * c);
                        if ((unsigned)(pk >> 32) == want) {
                            union { unsigned u; float f; } cv; cv.u = (unsigned)pk;
                            outn[c] = cv.f;
                            done |= (1u << c);
                        }
                    }
                }
                if (__all(done == 0xFFu)) break;
                __builtin_amdgcn_s_sleep(1);
            }
#pragma unroll
            for (int c = 0; c < 8; ++c) outp[c] = outn[c];
#pragma unroll
            for (int c = 0; c < 4; ++c) xv[c] = fmaxf(xvn[c], 0.0f);
            Rcur = Rn;
        }
    }

    // ---- one-time cross-block barrier: all hs stores visible for epilogue ----
    unsigned* cnt = barrier_cnt + b * 32;   // 128B-strided per-batch lines
    __syncthreads();                        // s_barrier implies vmcnt(0) drain
    if (tid == 0) {
        asm volatile("s_waitcnt vmcnt(0)" ::: "memory");
        __hip_atomic_fetch_add(cnt, 1u, __ATOMIC_RELAXED, __HIP_MEMORY_SCOPE_AGENT);
        while (ldu_agent(cnt) < 32u) __builtin_amdgcn_s_sleep(2);
    }
    __syncthreads();

    // ---- epilogue: os[t,b,o] = sum_h hs[t,b,h]*relu(W_h2o[o,h])*exist ----
    {
        int widx = (hg << 3) | wid;         // 0..255 per batch; 2 pairs each
#pragma unroll
        for (int r = 0; r < 2; ++r) {
            int p = widx * 2 + r;           // 0..511
            int t = p >> 3, o = p & 7;
            const float* hrow = hs + ((size_t)t * B_N + b) * H_N;
            float acc = 0.0f;
#pragma unroll
            for (int c = 0; c < 7; ++c) {   // c==7 masked out (no exist)
                int j = lane + 64 * c;
                float w = fmaxf(W_h2o[o * H_N + j], 0.0f);
                if (j >= 410) w = 0.0f;
                acc = fmaf(ldf_agent(hrow + j), w, acc);
            }
#pragma unroll
            for (int off = 32; off >= 1; off >>= 1) acc += __shfl_xor(acc, off, 64);
            if (lane == 0) os[t * (B_N * O_N) + b * O_N + o] = acc;
        }
    }
}

extern "C" void kernel_launch(void* const* d_in, const int* in_sizes, int n_in,
                              void* d_out, int out_size, void* d_ws, size_t ws_size,
                              hipStream_t stream) {
    (void)in_sizes; (void)n_in; (void)out_size; (void)ws_size;
    const float* x      = (const float*)d_in[0];
    const float* Rs     = (const float*)d_in[1];
    const float* W_x2h  = (const float*)d_in[2];
    const float* W_h2h  = (const float*)d_in[3];
    const float* b_h2h  = (const float*)d_in[4];
    const float* W_h2o  = (const float*)d_in[5];
    const float* W_attn = (const float*)d_in[6];
    const float* b_attn = (const float*)d_in[7];
    const float* kappa  = (const float*)d_in[8];
    float* out = (float*)d_out;

    u64* comm     = (u64*)d_ws;                                   // 2*8*512*8 = 65536 B
    unsigned* cnt = (unsigned*)((char*)d_ws + 2 * B_N * H_N * 8); // 8*32*4 = 1024 B

    // zero comm tags + barrier counters every call (graph-capture-legal)
    hipMemsetAsync(d_ws, 0, 2 * B_N * H_N * 8 + B_N * 32 * 4, stream);
    rnn_scan<<<dim3(256), dim3(512), 0, stream>>>(
        x, Rs, W_x2h, W_h2h, b_h2h, W_h2o, W_attn, b_attn, kappa, out, comm, cnt);
}

// Round 5
// 282.397 us; speedup vs baseline: 1.5085x; 1.5085x over previous
//
#include <hip/hip_runtime.h>

// SimpleRNN: T=64, B=8, H=512, I=256, O=8, G=4, GS=64
// sign: +1 for j<=408, -1 for j>=409; exist: j<410
// chunk c: j = lane + 64c. c<=5 -> sign +1; c==7 -> sign -1 (exist=0);
// c==6 -> lane<=24: +1, lane==25: -1 (exists), lane>=26: no exist.
#define T_N 64
#define B_N 8
#define H_N 512
#define I_N 256
#define O_N 8
#define G_N 4

constexpr float DT_  = 0.02f;
constexpr float AX_  = 0.2f;    // DT/0.1
constexpr float AW_  = 0.02f;   // DT/1.0
constexpr float OMAW = 1.0f - AW_;

// Agent-scope coherent ops (sc0/sc1): bypass non-coherent L1/L2, never
// allocate there -> no stale copies, no fences needed.
__device__ __forceinline__ float ldf_agent(const float* p) {
    return __hip_atomic_load(p, __ATOMIC_RELAXED, __HIP_MEMORY_SCOPE_AGENT);
}
__device__ __forceinline__ void stf_agent(float* p, float v) {
    __hip_atomic_store(p, v, __ATOMIC_RELAXED, __HIP_MEMORY_SCOPE_AGENT);
}
__device__ __forceinline__ unsigned ldu_agent(const unsigned* p) {
    return __hip_atomic_load(p, __ATOMIC_RELAXED, __HIP_MEMORY_SCOPE_AGENT);
}
__device__ __forceinline__ void stu_agent(unsigned* p, unsigned v) {
    __hip_atomic_store(p, v, __ATOMIC_RELAXED, __HIP_MEMORY_SCOPE_AGENT);
}

__device__ __forceinline__ float fast_tanh_pos(float x) {
    // x >= 0; exact at 0 and +inf. tanh(x) = 1 - 2/(e^{2x}+1)
    float ex = __expf(2.0f * x);
    return 1.0f - 2.0f / (ex + 1.0f);
}

// 256 blocks x 1024 threads; wave owns one h. b = bk&7, hg = bk>>3,
// h = hg*16 + wid. Per step: producers store values then ONE tagged flag per
// block (after vmcnt-drain + block barrier); wave 0 of each consumer block
// polls the 32 flags of its batch (1 flag/lane, 128B-strided), gathers the
// 512-value row once, and broadcasts via LDS.
__global__ __launch_bounds__(1024) void rnn_scan(
    const float* __restrict__ x, const float* __restrict__ Rs,
    const float* __restrict__ W_x2h, const float* __restrict__ W_h2h,
    const float* __restrict__ b_h2h, const float* __restrict__ W_h2o,
    const float* __restrict__ W_attn, const float* __restrict__ b_attn,
    const float* __restrict__ kappa, float* __restrict__ d_out,
    unsigned* __restrict__ flags,      // [2][B][32] u32, stride 32 u32 (128B)
    unsigned* __restrict__ barrier_cnt,
    float* __restrict__ vals)          // [2][B][H] f32
{
    float* os = d_out;                      // [T][B][O]
    float* hs = d_out + T_N * B_N * O_N;    // [T][B][H]

    __shared__ float s_out[H_N];

    const int tid  = threadIdx.x;
    const int wid  = tid >> 6;              // 0..15
    const int lane = tid & 63;
    const int bk   = blockIdx.x;            // 0..255
    const int b    = bk & 7;                // XCD-pinned batch (heuristic)
    const int hg   = bk >> 3;               // 0..31
    const int h    = (hg << 4) | wid;       // 0..511
    const int c_d  = h >> 6;                // chunk holding the diagonal
    const int dl   = h & 63;                // its lane

    // ---- loop-invariant constants (registers only) ----
    float ea[G_N][7];
#pragma unroll
    for (int g = 0; g < G_N; ++g)
#pragma unroll
        for (int c = 0; c < 7; ++c) {
            int j = lane + 64 * c;
            float w = fmaxf(W_attn[g * H_N + j], 0.0f);
            float m = (j <= 408) ? 1.0f : ((j == 409) ? -1.0f : 0.0f);
            ea[g][c] = w * m;
        }

    // x-side: ex = Wxp + wx (>=0); bwx = AW*Wxp
    float ex[4], bwx[4];
#pragma unroll
    for (int c = 0; c < 4; ++c) {
        ex[c]  = fmaxf(W_x2h[h * I_N + lane + 64 * c], 0.0f);
        bwx[c] = AW_ * ex[c];
    }
    // h2h: se = sign*(Whp+wh); bwh = AW*Whp
    float se[8], bwh[8];
#pragma unroll
    for (int c = 0; c < 8; ++c) {
        int j = lane + 64 * c;
        float s = (j <= 408) ? 1.0f : -1.0f;
        float w = fmaxf(W_h2h[h * H_N + j], 0.0f);
        se[c]  = (j == h) ? 0.0f : s * w;
        bwh[c] = AW_ * w;
    }
    const float bh = b_h2h[h];
    const float k0 = kappa[0], k1 = kappa[1], k2 = kappa[2];
    const float k3 = kappa[3], k4 = kappa[4], k5 = kappa[5];
    const float ba0 = b_attn[0], ba1 = b_attn[1], ba2 = b_attn[2], ba3 = b_attn[3];

    float st = 0.0f;

    float xv[4];
#pragma unroll
    for (int c = 0; c < 4; ++c) xv[c] = fmaxf(x[(size_t)b * I_N + lane + 64 * c], 0.0f);
    float Rcur = Rs[b];

    float outp[8];
#pragma unroll
    for (int c = 0; c < 8; ++c) outp[c] = 0.0f;   // t=0 inputs are zeros

    for (int t = 0; t < T_N; ++t) {
        // ---- 9 fused wave reductions: 4 attn logits, 4 x-dot group
        //      partials, 1 h2h dot ----
        float red[9];
#pragma unroll
        for (int g = 0; g < G_N; ++g) {
            float l = 0.0f;
#pragma unroll
            for (int c = 0; c < 7; ++c) l = fmaf(outp[c], ea[g][c], l);
            red[g] = l;
        }
#pragma unroll
        for (int c = 0; c < 4; ++c) red[4 + c] = ex[c] * xv[c];
        {
            float a = 0.0f;
#pragma unroll
            for (int c = 0; c < 8; ++c) a = fmaf(se[c], outp[c], a);
            red[8] = a;
        }
#pragma unroll
        for (int off = 32; off >= 1; off >>= 1) {
#pragma unroll
            for (int k = 0; k < 9; ++k) red[k] += __shfl_xor(red[k], off, 64);
        }

        // ---- softmax over 4 logits (bounded ~|10|, no max-shift needed) ----
        float e0 = __expf(red[0] + ba0), e1 = __expf(red[1] + ba1);
        float e2 = __expf(red[2] + ba2), e3 = __expf(red[3] + ba3);
        float inv = 4.0f / (e0 + e1 + e2 + e3);     // fold *G
        float aw0 = e0 * inv, aw1 = e1 * inv, aw2 = e2 * inv, aw3 = e3 * inv;

        float total = red[4] * aw0 + red[5] * aw1 + red[6] * aw2 + red[7] * aw3
                    + red[8] + bh;

        st = st * (1.0f - AX_) + total * AX_;
        float no = fast_tanh_pos(fmaxf(st, 0.0f));

        // ---- publish value (comm slot + hs), fire-and-forget ----
        const int slot = t & 1;
        float* vrow = vals + ((size_t)slot * B_N + b) * H_N;
        if (lane == 0) {
            if (t + 1 < T_N) stf_agent(vrow + h, no);
            stf_agent(&hs[((size_t)t * B_N + b) * H_N + h], no);
        }

        if (t + 1 == T_N) break;   // last step: no plasticity/sync needed

        // ---- next-step input prefetch (in flight during plasticity) ----
        const float* xr = x + ((size_t)(t + 1) * B_N + b) * I_N;
        float xvn[4];
#pragma unroll
        for (int c = 0; c < 4; ++c) xvn[c] = xr[lane + 64 * c];
        float Rn = Rs[(t + 1) * B_N + b];

        // ---- plasticity update (overlaps the store round trip) ----
        float xin[4] = { xv[0] * aw0, xv[1] * aw1, xv[2] * aw2, xv[3] * aw3 };
        float dr = DT_ * Rcur;
        float k1n = k1 * no, k2n = k2 * no, k4n = k4 * no, k5n = k5 * no;
#pragma unroll
        for (int c = 0; c < 4; ++c) {
            float hx = fmaf(k2n, xin[c], fmaf(k0, xin[c], k1n));
            ex[c] = fmaxf(fmaf(ex[c], OMAW, fmaf(dr, hx, bwx[c])), 0.0f);
        }
#pragma unroll
        for (int c = 0; c < 8; ++c) {
            float hh = fmaf(k5n, outp[c], fmaf(k3, outp[c], k4n));
            float a = se[c] * OMAW, p = fmaf(dr, hh, bwh[c]);
            float r;
            if (c <= 5)      r = fmaxf(a + p, 0.0f);
            else if (c == 7) r = fminf(a - p, 0.0f);
            else             r = (lane <= 24) ? fmaxf(a + p, 0.0f)
                                              : fminf(a - p, 0.0f);
            if (c == c_d && lane == dl) r = 0.0f;   // keep diagonal at 0
            se[c] = r;
        }

        // ---- drain own stores to LLC, then one tagged flag per block ----
        asm volatile("s_waitcnt vmcnt(0)" ::: "memory");  // per-wave store ack
        __syncthreads();                                  // all 16 waves ack'd
        unsigned* fbase = flags + ((size_t)slot * B_N + b) * 32 * 32;
        if (tid == 0) stu_agent(fbase + hg * 32, (unsigned)(t + 1));

        // ---- wave 0: poll 32 spread flags (1/lane), gather row, stage LDS ----
        if (wid == 0) {
            const unsigned want = (unsigned)(t + 1);
            bool ready = (lane >= 32);
            while (true) {
                if (!ready) ready = (ldu_agent(fbase + lane * 32) == want);
                if (__all(ready)) break;
                __builtin_amdgcn_s_sleep(1);
            }
            float tmp[8];
#pragma unroll
            for (int c = 0; c < 8; ++c) tmp[c] = ldf_agent(vrow + lane + 64 * c);
#pragma unroll
            for (int c = 0; c < 8; ++c) s_out[lane + 64 * c] = tmp[c];
        }
        __syncthreads();

#pragma unroll
        for (int c = 0; c < 8; ++c) outp[c] = s_out[lane + 64 * c];
#pragma unroll
        for (int c = 0; c < 4; ++c) xv[c] = fmaxf(xvn[c], 0.0f);
        Rcur = Rn;
    }

    // ---- one-time cross-block barrier: all hs stores visible for epilogue ----
    unsigned* cnt = barrier_cnt + b * 32;   // 128B-strided per-batch lines
    asm volatile("s_waitcnt vmcnt(0)" ::: "memory");
    __syncthreads();
    if (tid == 0) {
        __hip_atomic_fetch_add(cnt, 1u, __ATOMIC_RELAXED, __HIP_MEMORY_SCOPE_AGENT);
        while (ldu_agent(cnt) < 32u) __builtin_amdgcn_s_sleep(2);
    }
    __syncthreads();

    // ---- epilogue: os[t,b,o] = sum_h hs[t,b,h]*relu(W_h2o[o,h])*exist ----
    {
        int v = (hg << 4) | wid;   // 0..511 -> (t,o)
        int t = v >> 3;
        int o = v & 7;
        const float* hrow = hs + ((size_t)t * B_N + b) * H_N;
        float acc = 0.0f;
#pragma unroll
        for (int c = 0; c < 7; ++c) {   // c==7 has no exist
            int j = lane + 64 * c;
            float w = fmaxf(W_h2o[o * H_N + j], 0.0f);
            if (j >= 410) w = 0.0f;
            acc = fmaf(ldf_agent(hrow + j), w, acc);
        }
#pragma unroll
        for (int off = 32; off >= 1; off >>= 1) acc += __shfl_xor(acc, off, 64);
        if (lane == 0) os[t * (B_N * O_N) + b * O_N + o] = acc;
    }
}

extern "C" void kernel_launch(void* const* d_in, const int* in_sizes, int n_in,
                              void* d_out, int out_size, void* d_ws, size_t ws_size,
                              hipStream_t stream) {
    (void)in_sizes; (void)n_in; (void)out_size; (void)ws_size;
    const float* x      = (const float*)d_in[0];
    const float* Rs     = (const float*)d_in[1];
    const float* W_x2h  = (const float*)d_in[2];
    const float* W_h2h  = (const float*)d_in[3];
    const float* b_h2h  = (const float*)d_in[4];
    const float* W_h2o  = (const float*)d_in[5];
    const float* W_attn = (const float*)d_in[6];
    const float* b_attn = (const float*)d_in[7];
    const float* kappa  = (const float*)d_in[8];
    float* out = (float*)d_out;

    // d_ws layout: [flags 64KB][cnt 1KB][vals 32KB]
    unsigned* flags = (unsigned*)d_ws;                       // 2*8*32*32*4 = 65536
    unsigned* cnt   = (unsigned*)((char*)d_ws + 65536);      // 8*32*4 = 1024
    float*    vals  = (float*)((char*)d_ws + 65536 + 1024);  // 2*8*512*4 = 32768

    // zero flags + counters every call (vals are gated by flags; no clear)
    hipMemsetAsync(d_ws, 0, 65536 + 1024, stream);
    rnn_scan<<<dim3(256), dim3(1024), 0, stream>>>(
        x, Rs, W_x2h, W_h2h, b_h2h, W_h2o, W_attn, b_attn, kappa, out,
        flags, cnt, vals);
}